// Round 3
// baseline (1034.266 us; speedup 1.0000x reference)
//
#include <hip/hip_runtime.h>
#include <stdint.h>
#include <stddef.h>

typedef __attribute__((ext_vector_type(8))) short short8;
typedef __attribute__((ext_vector_type(4))) float float4v;

#define T_SEQ 2048
#define D_MODEL 1024
#define NH 16
#define HD 64

static __device__ __forceinline__ unsigned short f2bf(float f) {
  unsigned u = __builtin_bit_cast(unsigned, f);
  u += 0x7fffu + ((u >> 16) & 1u);
  return (unsigned short)(u >> 16);
}
static __device__ __forceinline__ float bf2f(unsigned short h) {
  unsigned u = ((unsigned)h) << 16;
  return __builtin_bit_cast(float, u);
}
static __device__ __forceinline__ float4v mfma16(short8 a, short8 b, float4v c) {
  return __builtin_amdgcn_mfma_f32_16x16x32_bf16(a, b, c, 0, 0, 0);
}
// fp32 -> 3 bf16 terms (sum reproduces f to ~2^-27 rel)
static __device__ __forceinline__ void split3(float f, unsigned short& h0,
                                              unsigned short& h1, unsigned short& h2) {
  h0 = f2bf(f);
  float r1 = f - bf2f(h0);
  h1 = f2bf(r1);
  float r2 = r1 - bf2f(h1);
  h2 = f2bf(r2);
}
// fp32 -> 2 bf16 terms (~2^-18 rel)
static __device__ __forceinline__ void split2(float f, unsigned short& h0, unsigned short& h1) {
  h0 = f2bf(f);
  h1 = f2bf(f - bf2f(h0));
}

// ---------------- eta tables ----------------
__global__ void eta_kernel(const float* theta, float* E, float* Einv) {
  int i = blockIdx.x * blockDim.x + threadIdx.x;
  if (i >= T_SEQ) return;
  float th = theta[0];
  float h = log1pf(expf(th));            // softplus
  float t = 1.0f + h * (float)i;         // T0 = 1
  float eta = 3.0f * logf(t);            // C_LOG = 3
  eta = fminf(fmaxf(eta, -50.0f), 50.0f);
  E[i] = expf(eta);
  Einv[i] = expf(-eta);
}

// ---------------- LayerNorm (fp32 in) -> 3-way split y ----------------
__global__ __launch_bounds__(256) void ln_kernel(const float* x, const float* wgt,
                          unsigned short* y0, unsigned short* y1, unsigned short* y2) {
  int row = blockIdx.x;
  int tid = threadIdx.x;
  const float* xr = x + (size_t)row * D_MODEL;
  float v[4];
  float sum = 0.f, ssq = 0.f;
  for (int it = 0; it < 4; ++it) {
    float f = xr[tid + 256 * it];
    v[it] = f;
    sum += f; ssq += f * f;
  }
  for (int off = 32; off >= 1; off >>= 1) {
    sum += __shfl_xor(sum, off, 64);
    ssq += __shfl_xor(ssq, off, 64);
  }
  __shared__ float rs[4], rq[4];
  int w = tid >> 6;
  if ((tid & 63) == 0) { rs[w] = sum; rq[w] = ssq; }
  __syncthreads();
  sum = rs[0] + rs[1] + rs[2] + rs[3];
  ssq = rq[0] + rq[1] + rq[2] + rq[3];
  float mu = sum * (1.0f / D_MODEL);
  float var = ssq * (1.0f / D_MODEL) - mu * mu;
  float rstd = rsqrtf(var + 1e-5f);
  for (int it = 0; it < 4; ++it) {
    int d = tid + 256 * it;
    float y = (v[it] - mu) * rstd * wgt[d];
    unsigned short h0, h1, h2;
    split3(y, h0, h1, h2);
    size_t o = (size_t)row * D_MODEL + d;
    y0[o] = h0; y1[o] = h1; y2[o] = h2;
  }
}

// ---------------- attn_w (fp32) -> split3; W2 only for rows < 2048 (Q,K) ----------------
__global__ __launch_bounds__(256) void conv_w3(const float* src, unsigned short* W0,
                                               unsigned short* W1, unsigned short* W2) {
  size_t base = ((size_t)blockIdx.x * 256 + threadIdx.x) * 8;
  int row = (int)(base >> 10);
  short8 a, b, c;
  for (int j = 0; j < 8; ++j) {
    unsigned short h0, h1, h2;
    split3(src[base + j], h0, h1, h2);
    a[j] = (short)h0; b[j] = (short)h1; c[j] = (short)h2;
  }
  *(short8*)(W0 + base) = a;
  *(short8*)(W1 + base) = b;
  if (row < 2048) *(short8*)(W2 + base) = c;
}

// ---------------- proj_w (fp32) -> split2 ----------------
__global__ __launch_bounds__(256) void conv_pw(const float* src, unsigned short* P0,
                                               unsigned short* P1) {
  size_t base = ((size_t)blockIdx.x * 256 + threadIdx.x) * 8;
  short8 a, b;
  for (int j = 0; j < 8; ++j) {
    unsigned short h0, h1;
    split2(src[base + j], h0, h1);
    a[j] = (short)h0; b[j] = (short)h1;
  }
  *(short8*)(P0 + base) = a;
  *(short8*)(P1 + base) = b;
}

// ---------------- Q,K GEMM: fp32-grade via 6-term split MFMA ----------------
// C[m][e] = sum_d y[m][d] * W[e][d];  M=4096, N=2048 (Q,K), K=1024
__global__ __launch_bounds__(256) void qkv_qk(
    const unsigned short* y0, const unsigned short* y1, const unsigned short* y2,
    const unsigned short* W0, const unsigned short* W1, const unsigned short* W2,
    float* Qf, float* Kf) {
  int tid = threadIdx.x;
  int w = tid >> 6, lane = tid & 63, q4 = lane >> 4, ln = lane & 15;
  int n0 = blockIdx.x * 64;          // 0..2047
  int m0 = blockIdx.y * 128;
  float4v zero = {0.f, 0.f, 0.f, 0.f};
  float4v acc[2][4];
  for (int mt = 0; mt < 2; ++mt)
    for (int c = 0; c < 4; ++c) acc[mt][c] = zero;

  for (int k0 = 0; k0 < D_MODEL; k0 += 32) {
    short8 a0[2], a1[2], a2[2], b0[4], b1[4], b2[4];
    for (int mt = 0; mt < 2; ++mt) {
      size_t off = (size_t)(m0 + w * 32 + mt * 16 + ln) * D_MODEL + k0 + q4 * 8;
      a0[mt] = *(const short8*)(y0 + off);
      a1[mt] = *(const short8*)(y1 + off);
      a2[mt] = *(const short8*)(y2 + off);
    }
    for (int c = 0; c < 4; ++c) {
      size_t off = (size_t)(n0 + c * 16 + ln) * D_MODEL + k0 + q4 * 8;
      b0[c] = *(const short8*)(W0 + off);
      b1[c] = *(const short8*)(W1 + off);
      b2[c] = *(const short8*)(W2 + off);
    }
    for (int mt = 0; mt < 2; ++mt)
      for (int c = 0; c < 4; ++c) {
        acc[mt][c] = mfma16(a0[mt], b0[c], acc[mt][c]);
        acc[mt][c] = mfma16(a1[mt], b0[c], acc[mt][c]);
        acc[mt][c] = mfma16(a0[mt], b1[c], acc[mt][c]);
        acc[mt][c] = mfma16(a1[mt], b1[c], acc[mt][c]);
        acc[mt][c] = mfma16(a0[mt], b2[c], acc[mt][c]);
        acc[mt][c] = mfma16(a2[mt], b0[c], acc[mt][c]);
      }
  }
  int region = n0 >> 10;            // 0=Q 1=K
  int h = (n0 & 1023) >> 6;
  float* dst = region ? Kf : Qf;
  for (int mt = 0; mt < 2; ++mt)
    for (int c = 0; c < 4; ++c)
      for (int r = 0; r < 4; ++r) {
        int gm = m0 + w * 32 + mt * 16 + q4 * 4 + r;
        int bi = gm >> 11, t = gm & 2047;
        int d = c * 16 + ln;
        dst[((size_t)(bi * NH + h) * T_SEQ + t) * HD + d] = acc[mt][c][r];
      }
}

// ---------------- V GEMM (3-term, bf16-out, transposed [b,h,d,t]) ----------------
__global__ __launch_bounds__(256) void qkv_v(
    const unsigned short* y0, const unsigned short* y1,
    const unsigned short* W0, const unsigned short* W1, unsigned short* VbT) {
  int tid = threadIdx.x;
  int w = tid >> 6, lane = tid & 63, q4 = lane >> 4, ln = lane & 15;
  int n0 = 2048 + blockIdx.x * 64;   // V region rows of attn_w
  int m0 = blockIdx.y * 128;
  float4v zero = {0.f, 0.f, 0.f, 0.f};
  float4v acc[2][4];
  for (int mt = 0; mt < 2; ++mt)
    for (int c = 0; c < 4; ++c) acc[mt][c] = zero;

  for (int k0 = 0; k0 < D_MODEL; k0 += 32) {
    short8 a0[2], a1[2], b0[4], b1[4];
    for (int mt = 0; mt < 2; ++mt) {
      size_t off = (size_t)(m0 + w * 32 + mt * 16 + ln) * D_MODEL + k0 + q4 * 8;
      a0[mt] = *(const short8*)(y0 + off);
      a1[mt] = *(const short8*)(y1 + off);
    }
    for (int c = 0; c < 4; ++c) {
      size_t off = (size_t)(n0 + c * 16 + ln) * D_MODEL + k0 + q4 * 8;
      b0[c] = *(const short8*)(W0 + off);
      b1[c] = *(const short8*)(W1 + off);
    }
    for (int mt = 0; mt < 2; ++mt)
      for (int c = 0; c < 4; ++c) {
        acc[mt][c] = mfma16(a0[mt], b0[c], acc[mt][c]);
        acc[mt][c] = mfma16(a1[mt], b0[c], acc[mt][c]);
        acc[mt][c] = mfma16(a0[mt], b1[c], acc[mt][c]);
      }
  }
  int h = (n0 & 1023) >> 6;
  for (int mt = 0; mt < 2; ++mt)
    for (int c = 0; c < 4; ++c) {
      int tb = m0 + w * 32 + mt * 16 + q4 * 4;   // 4 consecutive t
      int bi = tb >> 11, t = tb & 2047;
      int d = c * 16 + ln;
      unsigned short tmp[4];
      for (int r = 0; r < 4; ++r) tmp[r] = f2bf(acc[mt][c][r]);
      *(uint64_t*)(VbT + ((size_t)((bi * NH + h) * HD + d) * T_SEQ + t)) =
          *(const uint64_t*)tmp;
    }
}

// ---------------- fused causal attention (flash-style, fp32-grade S) ----------------
__global__ __launch_bounds__(256) void attn_kernel(
    const float* Qf, const float* Kf, const unsigned short* VbT,
    const float* E, const float* Einv, unsigned short* Ob0, unsigned short* Ob1) {
  __shared__ unsigned short Plds[4][16][72];   // per-wave P tile, padded
  int tid = threadIdx.x;
  int w = tid >> 6, lane = tid & 63, q4 = lane >> 4, ln = lane & 15;
  int qt = blockIdx.x;
  int bh = blockIdx.y;
  int q0 = qt * 64;
  int ibase = q0 + w * 16;
  const float* Qb = Qf + (size_t)bh * T_SEQ * HD;
  const float* Kb = Kf + (size_t)bh * T_SEQ * HD;
  const unsigned short* Vb = VbT + (size_t)bh * HD * T_SEQ;

  // Q fragments, 3-way split, for 2 k-steps (d 0..31, 32..63)
  short8 qa[2][3];
  {
    const float* qp = Qb + (size_t)(ibase + ln) * HD;
    for (int ks = 0; ks < 2; ++ks) {
      float f[8];
      *(float4v*)&f[0] = *(const float4v*)(qp + ks * 32 + q4 * 8);
      *(float4v*)&f[4] = *(const float4v*)(qp + ks * 32 + q4 * 8 + 4);
      for (int j = 0; j < 8; ++j) {
        unsigned short h0, h1, h2;
        split3(f[j], h0, h1, h2);
        qa[ks][0][j] = (short)h0; qa[ks][1][j] = (short)h1; qa[ks][2][j] = (short)h2;
      }
    }
  }
  float ei[4];
  for (int r = 0; r < 4; ++r) ei[r] = E[ibase + q4 * 4 + r] * 0.125f; // fold 1/sqrt(64)

  float m_r[4] = {-3e38f, -3e38f, -3e38f, -3e38f};
  float l_r[4] = {0.f, 0.f, 0.f, 0.f};
  float4v zero = {0.f, 0.f, 0.f, 0.f};
  float4v oacc[4];
  for (int c = 0; c < 4; ++c) oacc[c] = zero;

  for (int jt = 0; jt <= qt; ++jt) {
    int j0 = jt * 64;
    bool diag = (jt == qt);
    float p[4][4];   // [c][r]: logits, then probabilities
    for (int c = 0; c < 4; ++c) {
      int jrow = j0 + c * 16 + ln;
      const float* kp = Kb + (size_t)jrow * HD;
      float4v s = zero;
      for (int ks = 0; ks < 2; ++ks) {
        float f[8];
        *(float4v*)&f[0] = *(const float4v*)(kp + ks * 32 + q4 * 8);
        *(float4v*)&f[4] = *(const float4v*)(kp + ks * 32 + q4 * 8 + 4);
        short8 k0v, k1v, k2v;
        for (int j = 0; j < 8; ++j) {
          unsigned short h0, h1, h2;
          split3(f[j], h0, h1, h2);
          k0v[j] = (short)h0; k1v[j] = (short)h1; k2v[j] = (short)h2;
        }
        // 6-term split product: fp32-grade S
        s = mfma16(qa[ks][0], k0v, s);
        s = mfma16(qa[ks][1], k0v, s);
        s = mfma16(qa[ks][0], k1v, s);
        s = mfma16(qa[ks][1], k1v, s);
        s = mfma16(qa[ks][0], k2v, s);
        s = mfma16(qa[ks][2], k0v, s);
      }
      float ein = Einv[jrow];
      for (int r = 0; r < 4; ++r) {
        float l = s[r] * ei[r] * ein;
        if (diag && jrow > ibase + q4 * 4 + r) l = -3e38f;   // causal mask
        p[c][r] = l;
      }
    }
    // online softmax (each row lives on the 16 lanes sharing q4)
    float alpha[4], mnew[4];
    for (int r = 0; r < 4; ++r) {
      float tm = fmaxf(fmaxf(p[0][r], p[1][r]), fmaxf(p[2][r], p[3][r]));
      for (int off = 8; off >= 1; off >>= 1) tm = fmaxf(tm, __shfl_xor(tm, off, 16));
      mnew[r] = fmaxf(m_r[r], tm);
      alpha[r] = expf(m_r[r] - mnew[r]);
      m_r[r] = mnew[r];
    }
    float rssum[4] = {0.f, 0.f, 0.f, 0.f};
    for (int c = 0; c < 4; ++c)
      for (int r = 0; r < 4; ++r) {
        float pv = expf(p[c][r] - mnew[r]);
        p[c][r] = pv;
        rssum[r] += pv;
      }
    for (int r = 0; r < 4; ++r) {
      for (int off = 8; off >= 1; off >>= 1) rssum[r] += __shfl_xor(rssum[r], off, 16);
      l_r[r] = l_r[r] * alpha[r] + rssum[r];
    }
    for (int c = 0; c < 4; ++c)
      for (int r = 0; r < 4; ++r) oacc[c][r] *= alpha[r];

    __syncthreads();   // prev iteration's P reads done before overwrite
    for (int c = 0; c < 4; ++c)
      for (int r = 0; r < 4; ++r)
        Plds[w][q4 * 4 + r][c * 16 + ln] = f2bf(p[c][r]);
    __syncthreads();   // writes visible before A-layout reads

    // P·V (V fragments directly from transposed global layout)
    for (int ks = 0; ks < 2; ++ks) {
      short8 pa = *(const short8*)&Plds[w][ln][ks * 32 + q4 * 8];
      for (int c = 0; c < 4; ++c) {
        short8 vb = *(const short8*)(Vb + (size_t)(c * 16 + ln) * T_SEQ + j0 + ks * 32 + q4 * 8);
        oacc[c] = mfma16(pa, vb, oacc[c]);
      }
    }
  }
  int b = bh >> 4, hh = bh & 15;
  for (int c = 0; c < 4; ++c)
    for (int r = 0; r < 4; ++r) {
      int i = ibase + q4 * 4 + r;
      float val = oacc[c][r] / l_r[r];
      unsigned short h0, h1;
      split2(val, h0, h1);
      size_t o = ((size_t)(b * T_SEQ + i)) * D_MODEL + hh * 64 + c * 16 + ln;
      Ob0[o] = h0; Ob1[o] = h1;
    }
}

// ---------------- output projection (3-term split, fp32 out) ----------------
__global__ __launch_bounds__(256) void proj_gemm(
    const unsigned short* A0, const unsigned short* A1,
    const unsigned short* P0, const unsigned short* P1, float* out) {
  int tid = threadIdx.x;
  int w = tid >> 6, lane = tid & 63, q4 = lane >> 4, ln = lane & 15;
  int n0 = blockIdx.x * 64;
  int m0 = blockIdx.y * 128;
  float4v zero = {0.f, 0.f, 0.f, 0.f};
  float4v acc[2][4];
  for (int mt = 0; mt < 2; ++mt)
    for (int c = 0; c < 4; ++c) acc[mt][c] = zero;

  for (int k0 = 0; k0 < D_MODEL; k0 += 32) {
    short8 a0[2], a1[2], b0[4], b1[4];
    for (int mt = 0; mt < 2; ++mt) {
      size_t off = (size_t)(m0 + w * 32 + mt * 16 + ln) * D_MODEL + k0 + q4 * 8;
      a0[mt] = *(const short8*)(A0 + off);
      a1[mt] = *(const short8*)(A1 + off);
    }
    for (int c = 0; c < 4; ++c) {
      size_t off = (size_t)(n0 + c * 16 + ln) * D_MODEL + k0 + q4 * 8;
      b0[c] = *(const short8*)(P0 + off);
      b1[c] = *(const short8*)(P1 + off);
    }
    for (int mt = 0; mt < 2; ++mt)
      for (int c = 0; c < 4; ++c) {
        acc[mt][c] = mfma16(a0[mt], b0[c], acc[mt][c]);
        acc[mt][c] = mfma16(a1[mt], b0[c], acc[mt][c]);
        acc[mt][c] = mfma16(a0[mt], b1[c], acc[mt][c]);
      }
  }
  for (int mt = 0; mt < 2; ++mt)
    for (int c = 0; c < 4; ++c)
      for (int r = 0; r < 4; ++r) {
        int gm = m0 + w * 32 + mt * 16 + q4 * 4 + r;
        out[(size_t)gm * D_MODEL + n0 + c * 16 + ln] = acc[mt][c][r];
      }
}

extern "C" void kernel_launch(void* const* d_in, const int* in_sizes, int n_in,
                              void* d_out, int out_size, void* d_ws, size_t ws_size,
                              hipStream_t stream) {
  const float* x      = (const float*)d_in[0];
  const float* ln_w   = (const float*)d_in[1];
  const float* attn_w = (const float*)d_in[2];
  const float* proj_w = (const float*)d_in[3];
  const float* theta  = (const float*)d_in[4];
  float* out = (float*)d_out;

  char* ws = (char*)d_ws;
  const size_t SZY  = (size_t)4096 * 1024 * 2;        // 8,388,608
  const size_t SZW  = (size_t)3072 * 1024 * 2;        // 6,291,456
  const size_t SZW2 = (size_t)2048 * 1024 * 2;        // 4,194,304
  const size_t SZQK = (size_t)2 * 16 * 2048 * 64 * 4; // 16,777,216

  unsigned short* y0 = (unsigned short*)(ws);
  unsigned short* y1 = (unsigned short*)(ws + SZY);
  unsigned short* y2 = (unsigned short*)(ws + 2 * SZY);
  unsigned short* W0 = (unsigned short*)(ws + 3 * SZY);
  unsigned short* W1 = (unsigned short*)(ws + 3 * SZY + SZW);
  unsigned short* W2 = (unsigned short*)(ws + 3 * SZY + 2 * SZW);
  float* Qf          = (float*)(ws + 3 * SZY + 2 * SZW + SZW2);
  float* Kf          = (float*)(ws + 3 * SZY + 2 * SZW + SZW2 + SZQK);
  float* E           = (float*)(ws + 3 * SZY + 2 * SZW + SZW2 + 2 * SZQK);
  float* Einv        = E + T_SEQ;
  // aliases into dead regions (y dead after qkv_*, then reused):
  unsigned short* Ob0 = y0;
  unsigned short* Ob1 = y1;
  unsigned short* PW0 = y2;
  unsigned short* PW1 = y2 + (size_t)1024 * 1024;
  // VbT scratch lives in d_out's low 8.39 MB (overwritten by proj at the end)
  unsigned short* VbT = (unsigned short*)d_out;

  size_t needed = 3 * SZY + 2 * SZW + SZW2 + 2 * SZQK + 2 * T_SEQ * 4;  // 75,513,856
  if (ws_size < needed) return;  // loud failure: output stays zero

  eta_kernel<<<dim3(8), dim3(256), 0, stream>>>(theta, E, Einv);
  ln_kernel<<<dim3(4096), dim3(256), 0, stream>>>(x, ln_w, y0, y1, y2);
  conv_w3<<<dim3(1536), dim3(256), 0, stream>>>(attn_w, W0, W1, W2);
  qkv_qk<<<dim3(32, 32), dim3(256), 0, stream>>>(y0, y1, y2, W0, W1, W2, Qf, Kf);
  qkv_v<<<dim3(16, 32), dim3(256), 0, stream>>>(y0, y1, W0, W1, VbT);
  attn_kernel<<<dim3(32, 32), dim3(256), 0, stream>>>(Qf, Kf, VbT, E, Einv, Ob0, Ob1);
  conv_pw<<<dim3(512), dim3(256), 0, stream>>>(proj_w, PW0, PW1);
  proj_gemm<<<dim3(16, 32), dim3(256), 0, stream>>>(Ob0, Ob1, PW0, PW1, out);
}